// Round 14
// baseline (596.129 us; speedup 1.0000x reference)
//
#include <hip/hip_runtime.h>

typedef __bf16 bf16;
typedef bf16 bf16x4 __attribute__((ext_vector_type(4)));
typedef bf16 bf16x8 __attribute__((ext_vector_type(8)));
typedef float f32x4 __attribute__((ext_vector_type(4)));

#define D_MODEL 1024
#define NHEAD   16
#define D_K     64
#define BATCH   8
#define SEQL    1024
#define MROWS   (BATCH*SEQL)   // 8192
#define MWORDS  ((size_t)BATCH*NHEAD*SEQL*SEQL)   // 134217728 mask words

// ---------------- f32 -> bf16 conversion (7 arrays in one launch) ----------------
struct Cvt7 {
    const float* s[7];
    bf16*        d[7];
    int          n[7];
};

__global__ __launch_bounds__(256) void cvt7_kernel(Cvt7 a) {
    const int y = blockIdx.y;
    const float* __restrict__ src = a.s[y];
    bf16* __restrict__ dst = a.d[y];
    const int n4 = a.n[y] >> 2;
    const int stride = gridDim.x * blockDim.x;
    for (int i = blockIdx.x * blockDim.x + threadIdx.x; i < n4; i += stride) {
        float4 v = ((const float4*)src)[i];
        bf16x4 o = { (bf16)v.x, (bf16)v.y, (bf16)v.z, (bf16)v.w };
        ((bf16x4*)dst)[i] = o;
    }
}

// ---------------- GEMM core (R1-proven m97 structure): C = A * B^T ----------------
#define BM 128
#define BN 128
#define BK 32

__device__ __forceinline__ void gemm_core(const bf16* __restrict__ A, const bf16* __restrict__ B,
                                          int bm, int bn, int K,
                                          bf16* lA, bf16* lB, f32x4 (&acc)[4][4]) {
    const int t = threadIdx.x;
    const int lane = t & 63, w = t >> 6;
    const int wr = w >> 1, wc = w & 1;
    const int r = lane & 15, kb = lane >> 4;

    for (int k0 = 0; k0 < K; k0 += BK) {
        __syncthreads();
        #pragma unroll
        for (int i = 0; i < 2; ++i) {
            const int off = i * 4096 + w * 1024 + lane * 16;
            const int row = off >> 6;
            const int cb  = off & 63;
            const bf16* srcA = A + (size_t)(bm + row) * K + k0 + (cb >> 1);
            const bf16* srcB = B + (size_t)(bn + row) * K + k0 + (cb >> 1);
            __builtin_amdgcn_global_load_lds(
                (const __attribute__((address_space(1))) unsigned int*)srcA,
                (__attribute__((address_space(3))) unsigned int*)((char*)lA + i * 4096 + w * 1024),
                16, 0, 0);
            __builtin_amdgcn_global_load_lds(
                (const __attribute__((address_space(1))) unsigned int*)srcB,
                (__attribute__((address_space(3))) unsigned int*)((char*)lB + i * 4096 + w * 1024),
                16, 0, 0);
        }
        __syncthreads();

        bf16x8 af[4], bfr[4];
        #pragma unroll
        for (int m = 0; m < 4; ++m)
            af[m] = *(const bf16x8*)(lA + (wr * 64 + m * 16 + r) * BK + kb * 8);
        #pragma unroll
        for (int n = 0; n < 4; ++n)
            bfr[n] = *(const bf16x8*)(lB + (wc * 64 + n * 16 + r) * BK + kb * 8);
        #pragma unroll
        for (int m = 0; m < 4; ++m)
            #pragma unroll
            for (int n = 0; n < 4; ++n)
                acc[m][n] = __builtin_amdgcn_mfma_f32_16x16x32_bf16(af[m], bfr[n], acc[m][n], 0, 0, 0);
    }
}

// ---------------- fused Q/K/V projections + mask bit-pack (one launch) ----------------
// R14: the mask's 512MB HBM crossing is dependency-free; proj3 is compute-bound using ~2 of
// 6.3 TB/s. Interleave 512 pack blocks among 1536 GEMM blocks (1-in-4 in dispatch order) so
// the mask stream crosses HBM UNDER the GEMM's compute time. Pack: wave reads 4x64 coalesced
// words, __ballot packs bit kv%64 of u64 kv/64 (bit L = lane L's word). Output 16MB -> Mp.
__global__ __launch_bounds__(256) void projpack_kernel(
        const bf16* __restrict__ xq, const bf16* __restrict__ xk, const bf16* __restrict__ xv,
        const bf16* __restrict__ Wqb, const bf16* __restrict__ Wkb, const bf16* __restrict__ Wvb,
        const float* __restrict__ bq, const float* __restrict__ bk, const float* __restrict__ bv,
        const unsigned int* __restrict__ mask, unsigned long long* __restrict__ Mp,
        bf16* __restrict__ Qp, bf16* __restrict__ Kp, bf16* __restrict__ Vt) {
    __shared__ bf16 lA[BM * BK], lB[BN * BK];
    const int bid = blockIdx.x;

    if ((bid & 3) == 3) {
        // ---- mask bit-pack path (512 blocks = 2048 waves) ----
        const int lane = threadIdx.x & 63;
        const int wid  = (((bid >> 2) * 256 + threadIdx.x) >> 6);   // 0..2047
        const size_t ngrp = MWORDS / 256;                            // 524288
        for (size_t i = wid; i < ngrp; i += 2048) {
            const unsigned int* base = mask + i * 256;
            const unsigned long long o0 = __ballot(base[0 * 64 + lane] != 0);
            const unsigned long long o1 = __ballot(base[1 * 64 + lane] != 0);
            const unsigned long long o2 = __ballot(base[2 * 64 + lane] != 0);
            const unsigned long long o3 = __ballot(base[3 * 64 + lane] != 0);
            if (lane < 4) {
                const unsigned long long v = lane == 0 ? o0 : lane == 1 ? o1 : lane == 2 ? o2 : o3;
                Mp[i * 4 + lane] = v;
            }
        }
        return;
    }

    // ---- GEMM path: projIdx in [0,1536) -> (z, bn, bm) ----
    const int projIdx = (bid >> 2) * 3 + (bid & 3);
    const int z   = projIdx / 512;
    const int rem = projIdx % 512;
    const int bm = (rem & 63) * BM;
    const int bn = (rem >> 6) * BN;
    const bf16* A    = (z == 0) ? xq  : (z == 1) ? xk  : xv;
    const bf16* Bm   = (z == 0) ? Wqb : (z == 1) ? Wkb : Wvb;
    const float* bias = (z == 0) ? bq : (z == 1) ? bk  : bv;

    f32x4 acc[4][4] = {};
    gemm_core(A, Bm, bm, bn, D_MODEL, lA, lB, acc);

    const int lane = threadIdx.x & 63, w = threadIdx.x >> 6;
    const int wr = w >> 1, wc = w & 1, r = lane & 15, g = lane >> 4;
    #pragma unroll
    for (int n = 0; n < 4; ++n) {
        const int col = bn + wc * 64 + n * 16 + r;
        const float bvl = bias[col];
        const int h = col >> 6, d = col & 63;
        #pragma unroll
        for (int m = 0; m < 4; ++m) {
            #pragma unroll
            for (int j = 0; j < 4; ++j) {
                const int row = bm + wr * 64 + m * 16 + g * 4 + j;
                const float v = acc[m][n][j] + bvl;
                const int b = row >> 10, s = row & (SEQL - 1);
                const int bh = b * NHEAD + h;
                if (z == 0) {
                    Qp[((size_t)bh * SEQL + s) * D_K + d] = (bf16)v;
                } else if (z == 1) {
                    Kp[((size_t)bh * SEQL + s) * D_K + d] = (bf16)v;
                } else {
                    Vt[((size_t)bh * D_K + d) * SEQL + s] = (bf16)v;
                }
            }
        }
    }
}

// ---------------- output projection: out = AO * Wo^T + bo (f32 out) ----------------
__global__ __launch_bounds__(256) void outproj_kernel(
        const bf16* __restrict__ AO, const bf16* __restrict__ Wob,
        const float* __restrict__ bo, float* __restrict__ out) {
    __shared__ bf16 lA[BM * BK], lB[BN * BK];
    const int bm = blockIdx.x * BM, bn = blockIdx.y * BN;
    f32x4 acc[4][4] = {};
    gemm_core(AO, Wob, bm, bn, D_MODEL, lA, lB, acc);

    const int lane = threadIdx.x & 63, w = threadIdx.x >> 6;
    const int wr = w >> 1, wc = w & 1, r = lane & 15, g = lane >> 4;
    #pragma unroll
    for (int n = 0; n < 4; ++n) {
        const int col = bn + wc * 64 + n * 16 + r;
        const float bvl = bo[col];
        #pragma unroll
        for (int m = 0; m < 4; ++m)
            #pragma unroll
            for (int j = 0; j < 4; ++j) {
                const int row = bm + wr * 64 + m * 16 + g * 4 + j;
                out[(size_t)row * D_MODEL + col] = acc[m][n][j] + bvl;
            }
    }
}

// ---------------- fused masked flash attention: packed-bit mask, K/V-only staging ----------------
// R12-base loop (proven), with mask staging replaced by the 16MB packed bitmask:
// the block's 64 rows x 16 tiles of bits = 8KB CONTIGUOUS in Mp, staged ONCE in the prologue
// (2 gload_lds/thread for the whole kernel). Per tile: 1 ds_read_b64 per lane (bits for row
// q=w*16+r), bit kv_local = (n*16+g*4+j). Staged per-tile traffic drops 32->16KB (K/V only,
// L2-resident via XCD remap) -> attn HBM ~0. LDS 32KB -> (256,4).
// Swapped QK^T (A=K, B=Q). No max-subtraction (|S|<~10 after *0.125); deferred row-sum.
__global__ __launch_bounds__(256, 4) void attn_kernel(
        const bf16* __restrict__ Qp, const bf16* __restrict__ Kp, const bf16* __restrict__ Vt,
        const unsigned long long* __restrict__ Mp, bf16* __restrict__ AO) {
    __shared__ char kbuf[8192];                  // K tile [64 s][128B], chunk-swizzled
    __shared__ char vbuf[8192];                  // V^T tile [64 d][128B], chunk-swizzled
    __shared__ bf16 plds[4][16 * 64];            // per-wave P tile (2KB each)
    __shared__ unsigned long long mbits[64][16]; // packed mask bits [row][tile] (8KB)
    const int lin = blockIdx.x + blockIdx.y * gridDim.x;
    const int xcd = lin & 7, pos = lin >> 3;
    const int bh  = xcd * 16 + (pos >> 4);
    const int qt  = pos & 15;
    const int b = bh >> 4, h = bh & 15;
    const int t = threadIdx.x, lane = t & 63, w = t >> 6;
    const int q0 = qt * 64;                      // block q-tile; wave w owns rows w*16 + r
    const int r = lane & 15, g = lane >> 4;

    const char* __restrict__ Kb = (const char*)(Kp + (size_t)bh * SEQL * D_K);
    const char* __restrict__ Vb = (const char*)(Vt + (size_t)bh * D_K * SEQL);

    // ---- prologue: stage this block's packed mask bits (8KB contiguous) ----
    const char* Mpb = (const char*)(Mp + ((size_t)bh * SEQL + q0) * 16);
    __builtin_amdgcn_global_load_lds(
        (const __attribute__((address_space(1))) unsigned int*)(Mpb + t * 16),
        (__attribute__((address_space(3))) unsigned int*)((char*)mbits + t * 16), 16, 0, 0);
    __builtin_amdgcn_global_load_lds(
        (const __attribute__((address_space(1))) unsigned int*)(Mpb + 4096 + t * 16),
        (__attribute__((address_space(3))) unsigned int*)((char*)mbits + 4096 + t * 16), 16, 0, 0);

    // Q fragment (B-operand): lane holds Q[q=r][kk*32+g*8..+8]; loaded once
    const bf16* __restrict__ Qh = Qp + ((size_t)bh * SEQL + q0 + w * 16) * D_K;
    bf16x8 qf[2];
    #pragma unroll
    for (int kk = 0; kk < 2; ++kk)
        qf[kk] = *(const bf16x8*)(Qh + r * D_K + kk * 32 + g * 8);

    f32x4 o[4] = {};              // O^T: o[n][j] = O[q=r][d = n*16 + g*4 + j]
    float psum = 0.f;
    char* P = (char*)plds[w];
    const int swz = (r & 7) << 4;

    for (int s0 = 0; s0 < SEQL; s0 += 64) {
        __syncthreads();   // prev tile's ds_reads done before overwrite (also drains prologue)
        // ---- stage K (2 instr), V (2 instr); linear dest, swizzled source ----
        #pragma unroll
        for (int i = 0; i < 2; ++i) {
            const int slot = i * 256 + t;
            const int row = slot >> 3, ch = slot & 7;
            const char* srcK = Kb + (size_t)(s0 + row) * 128 + ((ch * 16) ^ ((row & 7) << 4));
            const char* srcV = Vb + (size_t)row * (SEQL * 2) + s0 * 2 + ((ch * 16) ^ ((row & 7) << 4));
            __builtin_amdgcn_global_load_lds(
                (const __attribute__((address_space(1))) unsigned int*)srcK,
                (__attribute__((address_space(3))) unsigned int*)(kbuf + i * 4096 + w * 1024),
                16, 0, 0);
            __builtin_amdgcn_global_load_lds(
                (const __attribute__((address_space(1))) unsigned int*)srcV,
                (__attribute__((address_space(3))) unsigned int*)(vbuf + i * 4096 + w * 1024),
                16, 0, 0);
        }
        __syncthreads();   // staging visible (compiler drains vmcnt before barrier)

        // ---- QK^T: sf[n][j] = S[q=r][kv = n*16 + g*4 + j] ----
        f32x4 sf[4] = {};
        __builtin_amdgcn_s_setprio(1);
        #pragma unroll
        for (int n = 0; n < 4; ++n) {
            #pragma unroll
            for (int kk = 0; kk < 2; ++kk) {
                const int krow = n * 16 + r;
                bf16x8 kf = *(const bf16x8*)(kbuf + krow * 128 + ((kk * 64 + g * 16) ^ swz));
                sf[n] = __builtin_amdgcn_mfma_f32_16x16x32_bf16(kf, qf[kk], sf[n], 0, 0, 0);
            }
        }
        __builtin_amdgcn_s_setprio(0);
        // ---- mask bits + exp (no max subtraction; masked lanes contribute exactly 0) ----
        const unsigned long long sh = mbits[w * 16 + r][s0 >> 6] >> (g * 4);
        #pragma unroll
        for (int n = 0; n < 4; ++n) {
            const float p0 = ((sh >> (n * 16 + 0)) & 1ull) ? __expf(sf[n][0] * 0.125f) : 0.f;
            const float p1 = ((sh >> (n * 16 + 1)) & 1ull) ? __expf(sf[n][1] * 0.125f) : 0.f;
            const float p2 = ((sh >> (n * 16 + 2)) & 1ull) ? __expf(sf[n][2] * 0.125f) : 0.f;
            const float p3 = ((sh >> (n * 16 + 3)) & 1ull) ? __expf(sf[n][3] * 0.125f) : 0.f;
            psum += (p0 + p1) + (p2 + p3);
            bf16x4 pb = { (bf16)p0, (bf16)p1, (bf16)p2, (bf16)p3 };
            *(bf16x4*)(P + ((r * 128 + n * 32 + g * 8) ^ swz)) = pb;
        }
        // ---- PV: o[n] += V^T[d-block n] * P^T (P round-trip via per-wave LDS) ----
        bf16x8 pf0 = *(const bf16x8*)(P + ((r * 128 + 0 * 64 + g * 16) ^ swz));
        bf16x8 pf1 = *(const bf16x8*)(P + ((r * 128 + 1 * 64 + g * 16) ^ swz));
        __builtin_amdgcn_s_setprio(1);
        #pragma unroll
        for (int n = 0; n < 4; ++n) {
            const int vrow = n * 16 + r;
            bf16x8 vf0 = *(const bf16x8*)(vbuf + vrow * 128 + ((0 * 64 + g * 16) ^ swz));
            bf16x8 vf1 = *(const bf16x8*)(vbuf + vrow * 128 + ((1 * 64 + g * 16) ^ swz));
            o[n] = __builtin_amdgcn_mfma_f32_16x16x32_bf16(vf0, pf0, o[n], 0, 0, 0);
            o[n] = __builtin_amdgcn_mfma_f32_16x16x32_bf16(vf1, pf1, o[n], 0, 0, 0);
        }
        __builtin_amdgcn_s_setprio(0);
    }

    // deferred row-sum: lanes r, r+16, r+32, r+48 hold partials of row q=r
    psum += __shfl_xor(psum, 16);
    psum += __shfl_xor(psum, 32);
    const float inv = 1.0f / psum;

    const size_t rowbase = ((size_t)(b * SEQL + q0 + w * 16 + r)) * D_MODEL + h * D_K;
    #pragma unroll
    for (int n = 0; n < 4; ++n) {
        bf16x4 ob = { (bf16)(o[n][0] * inv), (bf16)(o[n][1] * inv),
                      (bf16)(o[n][2] * inv), (bf16)(o[n][3] * inv) };
        *(bf16x4*)(AO + rowbase + n * 16 + g * 4) = ob;
    }
}

// ---------------- launch ----------------
extern "C" void kernel_launch(void* const* d_in, const int* in_sizes, int n_in,
                              void* d_out, int out_size, void* d_ws, size_t ws_size,
                              hipStream_t stream) {
    const float* q    = (const float*)d_in[0];
    const float* k    = (const float*)d_in[1];
    const float* v    = (const float*)d_in[2];
    const unsigned int* mask = (const unsigned int*)d_in[3];
    const float* Wq = (const float*)d_in[4];
    const float* bq = (const float*)d_in[5];
    const float* Wk = (const float*)d_in[6];
    const float* bk = (const float*)d_in[7];
    const float* Wv = (const float*)d_in[8];
    const float* bv = (const float*)d_in[9];
    const float* Wo = (const float*)d_in[10];
    const float* bo = (const float*)d_in[11];

    char* ws = (char*)d_ws;
    const size_t MB = 1u << 20;
    bf16* qb  = (bf16*)(ws + 0 * MB);
    bf16* kb  = (bf16*)(ws + 16 * MB);
    bf16* vb  = (bf16*)(ws + 32 * MB);
    bf16* Wqb = (bf16*)(ws + 48 * MB);
    bf16* Wkb = (bf16*)(ws + 50 * MB);
    bf16* Wvb = (bf16*)(ws + 52 * MB);
    bf16* Wob = (bf16*)(ws + 54 * MB);
    bf16* Qp  = (bf16*)(ws + 56 * MB);
    bf16* Kp  = (bf16*)(ws + 72 * MB);
    bf16* Vt  = (bf16*)(ws + 88 * MB);
    bf16* AO  = (bf16*)(ws + 104 * MB);   // 120 MiB total
    // packed mask (16MB) in d_out's first half: dead until outproj, which runs strictly
    // after attn on this stream and overwrites all of d_out (R5-proven pattern).
    unsigned long long* Mp = (unsigned long long*)d_out;

    Cvt7 c;
    c.s[0] = q;  c.d[0] = qb;  c.n[0] = MROWS * D_MODEL;
    c.s[1] = k;  c.d[1] = kb;  c.n[1] = MROWS * D_MODEL;
    c.s[2] = v;  c.d[2] = vb;  c.n[2] = MROWS * D_MODEL;
    c.s[3] = Wq; c.d[3] = Wqb; c.n[3] = D_MODEL * D_MODEL;
    c.s[4] = Wk; c.d[4] = Wkb; c.n[4] = D_MODEL * D_MODEL;
    c.s[5] = Wv; c.d[5] = Wvb; c.n[5] = D_MODEL * D_MODEL;
    c.s[6] = Wo; c.d[6] = Wob; c.n[6] = D_MODEL * D_MODEL;
    cvt7_kernel<<<dim3(1024, 7), 256, 0, stream>>>(c);

    // 2048 blocks: 1536 GEMM + 512 mask-pack, interleaved 3:1 in dispatch order
    projpack_kernel<<<2048, 256, 0, stream>>>(
        qb, kb, vb, Wqb, Wkb, Wvb, bq, bk, bv, mask, Mp, Qp, Kp, Vt);

    attn_kernel<<<dim3(SEQL / 64, BATCH * NHEAD), 256, 0, stream>>>(Qp, Kp, Vt, Mp, AO);

    outproj_kernel<<<dim3(MROWS / BM, D_MODEL / BN), 256, 0, stream>>>(AO, Wob, bo, (float*)d_out);
}

// Round 15
// 289.635 us; speedup vs baseline: 2.0582x; 2.0582x over previous
//
#include <hip/hip_runtime.h>

typedef __bf16 bf16;
typedef bf16 bf16x4 __attribute__((ext_vector_type(4)));
typedef bf16 bf16x8 __attribute__((ext_vector_type(8)));
typedef float f32x4 __attribute__((ext_vector_type(4)));

#define D_MODEL 1024
#define NHEAD   16
#define D_K     64
#define BATCH   8
#define SEQL    1024
#define MROWS   (BATCH*SEQL)   // 8192

// ---------------- f32 -> bf16 conversion (7 arrays in one launch) ----------------
struct Cvt7 {
    const float* s[7];
    bf16*        d[7];
    int          n[7];
};

__global__ __launch_bounds__(256) void cvt7_kernel(Cvt7 a) {
    const int y = blockIdx.y;
    const float* __restrict__ src = a.s[y];
    bf16* __restrict__ dst = a.d[y];
    const int n4 = a.n[y] >> 2;
    const int stride = gridDim.x * blockDim.x;
    for (int i = blockIdx.x * blockDim.x + threadIdx.x; i < n4; i += stride) {
        float4 v = ((const float4*)src)[i];
        bf16x4 o = { (bf16)v.x, (bf16)v.y, (bf16)v.z, (bf16)v.w };
        ((bf16x4*)dst)[i] = o;
    }
}

// ---------------- GEMM core: C = A * B^T, BK=64 as TWO 32-col planes ----------------
// R15: each plane is byte-identical in layout/bank-behavior to the proven BK=32 tile
// (R1-proven m97 structure); staging queues 8 gload_lds then drains ONCE -> barrier count
// halves (64 -> 32 per GEMM). MFMA runs plane 0 then plane 1: K-accumulation order is
// bit-identical to BK=32. LDS 32KB -> 5 blocks/CU. R2 lesson: keep 128x128 tile at N=1024.
#define BM 128
#define BN 128
#define BK 64

__device__ __forceinline__ void gemm_core(const bf16* __restrict__ A, const bf16* __restrict__ B,
                                          int bm, int bn, int K,
                                          bf16* lA, bf16* lB, f32x4 (&acc)[4][4]) {
    const int t = threadIdx.x;
    const int lane = t & 63, w = t >> 6;
    const int wr = w >> 1, wc = w & 1;
    const int r = lane & 15, kb = lane >> 4;

    for (int k0 = 0; k0 < K; k0 += BK) {
        __syncthreads();
        #pragma unroll
        for (int i = 0; i < 4; ++i) {
            const int p = i >> 1, j = i & 1;               // plane (32-col half), half-of-plane
            const int off = j * 4096 + w * 1024 + lane * 16;
            const int row = off >> 6;                      // tile row (64 B per plane-row)
            const int cb  = off & 63;                      // byte within plane-row
            const bf16* srcA = A + (size_t)(bm + row) * K + k0 + p * 32 + (cb >> 1);
            const bf16* srcB = B + (size_t)(bn + row) * K + k0 + p * 32 + (cb >> 1);
            __builtin_amdgcn_global_load_lds(
                (const __attribute__((address_space(1))) unsigned int*)srcA,
                (__attribute__((address_space(3))) unsigned int*)((char*)lA + p * 8192 + j * 4096 + w * 1024),
                16, 0, 0);
            __builtin_amdgcn_global_load_lds(
                (const __attribute__((address_space(1))) unsigned int*)srcB,
                (__attribute__((address_space(3))) unsigned int*)((char*)lB + p * 8192 + j * 4096 + w * 1024),
                16, 0, 0);
        }
        __syncthreads();

        #pragma unroll
        for (int p = 0; p < 2; ++p) {                      // plane p = cols k0+p*32 .. +31
            bf16x8 af[4], bfr[4];
            #pragma unroll
            for (int m = 0; m < 4; ++m)
                af[m] = *(const bf16x8*)(lA + p * 4096 + (wr * 64 + m * 16 + r) * 32 + kb * 8);
            #pragma unroll
            for (int n = 0; n < 4; ++n)
                bfr[n] = *(const bf16x8*)(lB + p * 4096 + (wc * 64 + n * 16 + r) * 32 + kb * 8);
            #pragma unroll
            for (int m = 0; m < 4; ++m)
                #pragma unroll
                for (int n = 0; n < 4; ++n)
                    acc[m][n] = __builtin_amdgcn_mfma_f32_16x16x32_bf16(af[m], bfr[n], acc[m][n], 0, 0, 0);
        }
    }
}

// ---------------- Q/K/V projections (one launch, z = 0/1/2) ----------------
__global__ __launch_bounds__(256) void proj3_kernel(
        const bf16* __restrict__ xq, const bf16* __restrict__ xk, const bf16* __restrict__ xv,
        const bf16* __restrict__ Wqb, const bf16* __restrict__ Wkb, const bf16* __restrict__ Wvb,
        const float* __restrict__ bq, const float* __restrict__ bk, const float* __restrict__ bv,
        bf16* __restrict__ Qp, bf16* __restrict__ Kp, bf16* __restrict__ Vt) {
    __shared__ bf16 lA[BM * BK], lB[BN * BK];   // 16KB + 16KB
    const int z = blockIdx.z;
    const bf16* A    = (z == 0) ? xq  : (z == 1) ? xk  : xv;
    const bf16* Bm   = (z == 0) ? Wqb : (z == 1) ? Wkb : Wvb;
    const float* bias = (z == 0) ? bq : (z == 1) ? bk  : bv;
    const int bm = blockIdx.x * BM, bn = blockIdx.y * BN;

    f32x4 acc[4][4] = {};
    gemm_core(A, Bm, bm, bn, D_MODEL, lA, lB, acc);

    const int lane = threadIdx.x & 63, w = threadIdx.x >> 6;
    const int wr = w >> 1, wc = w & 1, r = lane & 15, g = lane >> 4;
    #pragma unroll
    for (int n = 0; n < 4; ++n) {
        const int col = bn + wc * 64 + n * 16 + r;
        const float bvl = bias[col];
        const int h = col >> 6, d = col & 63;
        #pragma unroll
        for (int m = 0; m < 4; ++m) {
            #pragma unroll
            for (int j = 0; j < 4; ++j) {
                const int row = bm + wr * 64 + m * 16 + g * 4 + j;
                const float v = acc[m][n][j] + bvl;
                const int b = row >> 10, s = row & (SEQL - 1);
                const int bh = b * NHEAD + h;
                if (z == 0) {
                    Qp[((size_t)bh * SEQL + s) * D_K + d] = (bf16)v;
                } else if (z == 1) {
                    Kp[((size_t)bh * SEQL + s) * D_K + d] = (bf16)v;
                } else {
                    Vt[((size_t)bh * D_K + d) * SEQL + s] = (bf16)v;
                }
            }
        }
    }
}

// ---------------- output projection: out = AO * Wo^T + bo (f32 out) ----------------
__global__ __launch_bounds__(256) void outproj_kernel(
        const bf16* __restrict__ AO, const bf16* __restrict__ Wob,
        const float* __restrict__ bo, float* __restrict__ out) {
    __shared__ bf16 lA[BM * BK], lB[BN * BK];
    const int bm = blockIdx.x * BM, bn = blockIdx.y * BN;
    f32x4 acc[4][4] = {};
    gemm_core(AO, Wob, bm, bn, D_MODEL, lA, lB, acc);

    const int lane = threadIdx.x & 63, w = threadIdx.x >> 6;
    const int wr = w >> 1, wc = w & 1, r = lane & 15, g = lane >> 4;
    #pragma unroll
    for (int n = 0; n < 4; ++n) {
        const int col = bn + wc * 64 + n * 16 + r;
        const float bvl = bo[col];
        #pragma unroll
        for (int m = 0; m < 4; ++m)
            #pragma unroll
            for (int j = 0; j < 4; ++j) {
                const int row = bm + wr * 64 + m * 16 + g * 4 + j;
                out[(size_t)row * D_MODEL + col] = acc[m][n][j] + bvl;
            }
    }
}

// ---------------- fused masked flash attention: R8/R11 proven best (UNCHANGED) ----------------
// Block-level LDS staging, line-granular global access, 40KB LDS, plain 2-barrier loop.
// R7/R9/R10: all explicit pipelining regressed. R11/R12: occupancy neutral. R13: volume
// neutral-negative. R14: cross-kernel fusion catastrophic. attn is at its structural floor
// for this decomposition: mask-HBM (~86us) + compute not further overlappable.
// Swapped QK^T (A=K, B=Q): lane (r,g) holds S[q=r][kv=n*16+g*4+j]. No max-subtraction
// (|S|<~10 after *0.125); row-sum deferred to 2 end shfl_xor.
__global__ __launch_bounds__(256, 4) void attn_kernel(
        const bf16* __restrict__ Qp, const bf16* __restrict__ Kp, const bf16* __restrict__ Vt,
        const unsigned int* __restrict__ mask, bf16* __restrict__ AO) {
    __shared__ char kbuf[8192];            // K tile [64 s][128B], chunk-swizzled
    __shared__ char vbuf[8192];            // V^T tile [64 d][128B], chunk-swizzled
    __shared__ char mbuf[16384];           // mask tile [64 q][256B], chunk-swizzled
    __shared__ bf16 plds[4][16 * 64];      // per-wave P tile (2 KiB each) -> 40KB total
    const int lin = blockIdx.x + blockIdx.y * gridDim.x;
    const int xcd = lin & 7, pos = lin >> 3;
    const int bh  = xcd * 16 + (pos >> 4);
    const int qt  = pos & 15;
    const int b = bh >> 4, h = bh & 15;
    const int t = threadIdx.x, lane = t & 63, w = t >> 6;
    const int q0 = qt * 64;                // block q-tile; wave w owns rows w*16 + r
    const int r = lane & 15, g = lane >> 4;

    const char* __restrict__ Kb = (const char*)(Kp + (size_t)bh * SEQL * D_K);
    const char* __restrict__ Vb = (const char*)(Vt + (size_t)bh * D_K * SEQL);
    const char* __restrict__ Mb = (const char*)(mask + ((size_t)bh * SEQL + q0) * SEQL);

    // Q fragment (B-operand): lane holds Q[q=r][kk*32+g*8..+8]; loaded once
    const bf16* __restrict__ Qh = Qp + ((size_t)bh * SEQL + q0 + w * 16) * D_K;
    bf16x8 qf[2];
    #pragma unroll
    for (int kk = 0; kk < 2; ++kk)
        qf[kk] = *(const bf16x8*)(Qh + r * D_K + kk * 32 + g * 8);

    f32x4 o[4] = {};              // O^T: o[n][j] = O[q=r][d = n*16 + g*4 + j]
    float psum = 0.f;
    char* P = (char*)plds[w];
    const int swz = (r & 7) << 4;

    for (int s0 = 0; s0 < SEQL; s0 += 64) {
        __syncthreads();   // prev tile's ds_reads done before overwrite
        // ---- stage K (2 instr), V (2 instr), M (4 instr); linear dest, swizzled source ----
        #pragma unroll
        for (int i = 0; i < 2; ++i) {
            const int slot = i * 256 + t;
            const int row = slot >> 3, ch = slot & 7;
            const char* srcK = Kb + (size_t)(s0 + row) * 128 + ((ch * 16) ^ ((row & 7) << 4));
            const char* srcV = Vb + (size_t)row * (SEQL * 2) + s0 * 2 + ((ch * 16) ^ ((row & 7) << 4));
            __builtin_amdgcn_global_load_lds(
                (const __attribute__((address_space(1))) unsigned int*)srcK,
                (__attribute__((address_space(3))) unsigned int*)(kbuf + i * 4096 + w * 1024),
                16, 0, 0);
            __builtin_amdgcn_global_load_lds(
                (const __attribute__((address_space(1))) unsigned int*)srcV,
                (__attribute__((address_space(3))) unsigned int*)(vbuf + i * 4096 + w * 1024),
                16, 0, 0);
        }
        #pragma unroll
        for (int i = 0; i < 4; ++i) {
            const int slot = i * 256 + t;
            const int row = slot >> 4, ch = slot & 15;
            const char* srcM = Mb + (size_t)row * (SEQL * 4) + s0 * 4 + ((ch * 16) ^ ((row & 7) << 4));
            __builtin_amdgcn_global_load_lds(
                (const __attribute__((address_space(1))) unsigned int*)srcM,
                (__attribute__((address_space(3))) unsigned int*)(mbuf + i * 4096 + w * 1024),
                16, 0, 0);
        }
        __syncthreads();   // staging visible (compiler drains vmcnt before barrier)

        // ---- QK^T: sf[n][j] = S[q=r][kv = n*16 + g*4 + j] ----
        f32x4 sf[4] = {};
        __builtin_amdgcn_s_setprio(1);
        #pragma unroll
        for (int n = 0; n < 4; ++n) {
            #pragma unroll
            for (int kk = 0; kk < 2; ++kk) {
                const int krow = n * 16 + r;
                bf16x8 kf = *(const bf16x8*)(kbuf + krow * 128 + ((kk * 64 + g * 16) ^ swz));
                sf[n] = __builtin_amdgcn_mfma_f32_16x16x32_bf16(kf, qf[kk], sf[n], 0, 0, 0);
            }
        }
        __builtin_amdgcn_s_setprio(0);
        // ---- mask + exp (no max subtraction; masked lanes contribute exactly 0) ----
        const int mrow = w * 16 + r;
        #pragma unroll
        for (int n = 0; n < 4; ++n) {
            const uint4 mv = *(const uint4*)(mbuf + mrow * 256 + ((n * 64 + g * 16) ^ swz));
            const float p0 = mv.x ? __expf(sf[n][0] * 0.125f) : 0.f;
            const float p1 = mv.y ? __expf(sf[n][1] * 0.125f) : 0.f;
            const float p2 = mv.z ? __expf(sf[n][2] * 0.125f) : 0.f;
            const float p3 = mv.w ? __expf(sf[n][3] * 0.125f) : 0.f;
            psum += (p0 + p1) + (p2 + p3);
            bf16x4 pb = { (bf16)p0, (bf16)p1, (bf16)p2, (bf16)p3 };
            *(bf16x4*)(P + ((r * 128 + n * 32 + g * 8) ^ swz)) = pb;
        }
        // ---- PV: o[n] += V^T[d-block n] * P^T (P round-trip via per-wave LDS) ----
        bf16x8 pf0 = *(const bf16x8*)(P + ((r * 128 + 0 * 64 + g * 16) ^ swz));
        bf16x8 pf1 = *(const bf16x8*)(P + ((r * 128 + 1 * 64 + g * 16) ^ swz));
        __builtin_amdgcn_s_setprio(1);
        #pragma unroll
        for (int n = 0; n < 4; ++n) {
            const int vrow = n * 16 + r;
            bf16x8 vf0 = *(const bf16x8*)(vbuf + vrow * 128 + ((0 * 64 + g * 16) ^ swz));
            bf16x8 vf1 = *(const bf16x8*)(vbuf + vrow * 128 + ((1 * 64 + g * 16) ^ swz));
            o[n] = __builtin_amdgcn_mfma_f32_16x16x32_bf16(vf0, pf0, o[n], 0, 0, 0);
            o[n] = __builtin_amdgcn_mfma_f32_16x16x32_bf16(vf1, pf1, o[n], 0, 0, 0);
        }
        __builtin_amdgcn_s_setprio(0);
    }

    // deferred row-sum: lanes r, r+16, r+32, r+48 hold partials of row q=r
    psum += __shfl_xor(psum, 16);
    psum += __shfl_xor(psum, 32);
    const float inv = 1.0f / psum;

    const size_t rowbase = ((size_t)(b * SEQL + q0 + w * 16 + r)) * D_MODEL + h * D_K;
    #pragma unroll
    for (int n = 0; n < 4; ++n) {
        bf16x4 ob = { (bf16)(o[n][0] * inv), (bf16)(o[n][1] * inv),
                      (bf16)(o[n][2] * inv), (bf16)(o[n][3] * inv) };
        *(bf16x4*)(AO + rowbase + n * 16 + g * 4) = ob;
    }
}

// ---------------- launch ----------------
extern "C" void kernel_launch(void* const* d_in, const int* in_sizes, int n_in,
                              void* d_out, int out_size, void* d_ws, size_t ws_size,
                              hipStream_t stream) {
    const float* q    = (const float*)d_in[0];
    const float* k    = (const float*)d_in[1];
    const float* v    = (const float*)d_in[2];
    const unsigned int* mask = (const unsigned int*)d_in[3];
    const float* Wq = (const float*)d_in[4];
    const float* bq = (const float*)d_in[5];
    const float* Wk = (const float*)d_in[6];
    const float* bk = (const float*)d_in[7];
    const float* Wv = (const float*)d_in[8];
    const float* bv = (const float*)d_in[9];
    const float* Wo = (const float*)d_in[10];
    const float* bo = (const float*)d_in[11];

    char* ws = (char*)d_ws;
    const size_t MB = 1u << 20;
    bf16* qb  = (bf16*)(ws + 0 * MB);
    bf16* kb  = (bf16*)(ws + 16 * MB);
    bf16* vb  = (bf16*)(ws + 32 * MB);
    bf16* Wqb = (bf16*)(ws + 48 * MB);
    bf16* Wkb = (bf16*)(ws + 50 * MB);
    bf16* Wvb = (bf16*)(ws + 52 * MB);
    bf16* Wob = (bf16*)(ws + 54 * MB);
    bf16* Qp  = (bf16*)(ws + 56 * MB);
    bf16* Kp  = (bf16*)(ws + 72 * MB);
    bf16* Vt  = (bf16*)(ws + 88 * MB);
    bf16* AO  = (bf16*)(ws + 104 * MB);   // 120 MiB total

    Cvt7 c;
    c.s[0] = q;  c.d[0] = qb;  c.n[0] = MROWS * D_MODEL;
    c.s[1] = k;  c.d[1] = kb;  c.n[1] = MROWS * D_MODEL;
    c.s[2] = v;  c.d[2] = vb;  c.n[2] = MROWS * D_MODEL;
    c.s[3] = Wq; c.d[3] = Wqb; c.n[3] = D_MODEL * D_MODEL;
    c.s[4] = Wk; c.d[4] = Wkb; c.n[4] = D_MODEL * D_MODEL;
    c.s[5] = Wv; c.d[5] = Wvb; c.n[5] = D_MODEL * D_MODEL;
    c.s[6] = Wo; c.d[6] = Wob; c.n[6] = D_MODEL * D_MODEL;
    cvt7_kernel<<<dim3(1024, 7), 256, 0, stream>>>(c);

    proj3_kernel<<<dim3(MROWS / BM, D_MODEL / BN, 3), 256, 0, stream>>>(
        qb, kb, vb, Wqb, Wkb, Wvb, bq, bk, bv, Qp, Kp, Vt);

    attn_kernel<<<dim3(SEQL / 64, BATCH * NHEAD), 256, 0, stream>>>(Qp, Kp, Vt, mask, AO);

    outproj_kernel<<<dim3(MROWS / BM, D_MODEL / BN), 256, 0, stream>>>(AO, Wob, bo, (float*)d_out);
}